// Round 6
// baseline (4629.705 us; speedup 1.0000x reference)
//
#include <hip/hip_runtime.h>
#include <hip/hip_bf16.h>

#define BB 256      // batch
#define TT 2048     // timesteps
#define DD 32       // obs dim
#define HH 64       // hidden
#define GG 256      // 4*H gates

__device__ __forceinline__ float fast_sig(float x) {
    return __builtin_amdgcn_rcpf(1.0f + __expf(-x));
}

// One wave per batch element. Lane l owns hidden unit l and computes all
// four of its gates. No barriers, no cross-wave exchange; the only LDS
// traffic is a same-wave h broadcast (in-order per-wave LDS ops make
// write->read safe without s_barrier).
__global__ __launch_bounds__(64, 1) void lstm_wave_kernel(
    const float* __restrict__ y,    // [B, T, D]
    const float* __restrict__ Wx,   // [D, 4H]
    const float* __restrict__ Wh,   // [H, 4H]
    const float* __restrict__ b,    // [4H]
    float* __restrict__ out)        // [B, T, H]
{
    const int l = threadIdx.x;        // hidden unit 0..63
    const int batch = blockIdx.x;

    __shared__ float hlds[HH];        // 256 B: h broadcast buffer

    // ---- per-lane weight columns for all 4 gates (384 VGPRs)
    float wx[4][DD];
#pragma unroll
    for (int g = 0; g < 4; ++g)
#pragma unroll
        for (int d = 0; d < DD; ++d)
            wx[g][d] = Wx[d * GG + g * HH + l];   // coalesced: lanes consecutive
    float wh[4][HH];
#pragma unroll
    for (int g = 0; g < 4; ++g)
#pragma unroll
        for (int k = 0; k < HH; ++k)
            wh[g][k] = Wh[k * GG + g * HH + l];
    float bj[4];
#pragma unroll
    for (int g = 0; g < 4; ++g) bj[g] = b[g * HH + l];

    float c = 0.0f, h = 0.0f;
    hlds[l] = 0.0f;                   // own-wave init; in-order LDS

    const float* ybase = y + (size_t)batch * (TT * DD);
    float* obase = out + (size_t)batch * (TT * HH);

    // x row double-buffered in registers, prefetched one full step ahead
    float4 xa[DD / 4], xb[DD / 4];
    {
        const float4* r0 = (const float4*)ybase;
#pragma unroll
        for (int q = 0; q < DD / 4; ++q) xa[q] = r0[q];
    }

#define STEP(XC, XN, TI)                                                      \
    {                                                                         \
        /* prefetch next row; in flight across the whole step (~900 cyc) */  \
        const int tn_ = ((TI) + 1 < TT) ? ((TI) + 1) : (TI);                  \
        const float4* nrow_ = (const float4*)(ybase + (size_t)tn_ * DD);      \
        _Pragma("unroll")                                                     \
        for (int q = 0; q < DD / 4; ++q) XN[q] = nrow_[q];                    \
        /* 8 independent accumulator chains: 4 gates x 2 */                   \
        float a0[4], a1[4];                                                   \
        _Pragma("unroll")                                                     \
        for (int g = 0; g < 4; ++g) { a0[g] = bj[g]; a1[g] = 0.0f; }          \
        _Pragma("unroll")                                                     \
        for (int q = 0; q < DD / 4; ++q) {                                    \
            float4 xv = XC[q];                                                \
            _Pragma("unroll")                                                 \
            for (int g = 0; g < 4; ++g) {                                     \
                a0[g] = fmaf(xv.x, wx[g][4 * q + 0], a0[g]);                  \
                a1[g] = fmaf(xv.y, wx[g][4 * q + 1], a1[g]);                  \
                a0[g] = fmaf(xv.z, wx[g][4 * q + 2], a0[g]);                  \
                a1[g] = fmaf(xv.w, wx[g][4 * q + 3], a1[g]);                  \
            }                                                                 \
        }                                                                     \
        /* h part: broadcast reads (all lanes same addr -> conflict-free) */  \
        const float4* hq_ = (const float4*)hlds;                              \
        _Pragma("unroll")                                                     \
        for (int k4 = 0; k4 < HH / 4; ++k4) {                                 \
            float4 hv = hq_[k4];                                              \
            _Pragma("unroll")                                                 \
            for (int g = 0; g < 4; ++g) {                                     \
                a0[g] = fmaf(hv.x, wh[g][4 * k4 + 0], a0[g]);                 \
                a1[g] = fmaf(hv.y, wh[g][4 * k4 + 1], a1[g]);                 \
                a0[g] = fmaf(hv.z, wh[g][4 * k4 + 2], a0[g]);                 \
                a1[g] = fmaf(hv.w, wh[g][4 * k4 + 3], a1[g]);                 \
            }                                                                 \
        }                                                                     \
        float ig_ = fast_sig(a0[0] + a1[0]);                                  \
        float fg_ = fast_sig(a0[1] + a1[1]);                                  \
        float gg_ = fmaf(2.0f, fast_sig(2.0f * (a0[2] + a1[2])), -1.0f);      \
        float og_ = fast_sig(a0[3] + a1[3]);                                  \
        c = fmaf(fg_, c, ig_ * gg_);                                          \
        h = og_ * fmaf(2.0f, fast_sig(2.0f * c), -1.0f);                      \
        hlds[l] = h;       /* same-wave write; next step's reads see it */    \
        obase[(size_t)(TI) * HH + l] = h;   /* coalesced 256B store */        \
    }

    for (int t = 0; t < TT; t += 2) {
        STEP(xa, xb, t);       // consume xa, prefetch xb
        STEP(xb, xa, t + 1);   // consume xb, prefetch xa
    }
#undef STEP
}

extern "C" void kernel_launch(void* const* d_in, const int* in_sizes, int n_in,
                              void* d_out, int out_size, void* d_ws, size_t ws_size,
                              hipStream_t stream) {
    const float* y  = (const float*)d_in[0];
    const float* Wx = (const float*)d_in[1];
    const float* Wh = (const float*)d_in[2];
    const float* b  = (const float*)d_in[3];
    float* out = (float*)d_out;

    lstm_wave_kernel<<<BB, HH, 0, stream>>>(y, Wx, Wh, b, out);
}

// Round 7
// 1514.723 us; speedup vs baseline: 3.0565x; 3.0565x over previous
//
#include <hip/hip_runtime.h>
#include <hip/hip_bf16.h>

#define BB 256      // batch
#define TT 2048     // timesteps
#define DD 32       // obs dim
#define HH 64       // hidden
#define GG 256      // 4*H gates

__device__ __forceinline__ float fast_sig(float x) {
    return __builtin_amdgcn_rcpf(1.0f + __expf(-x));
}
__device__ __forceinline__ float rdlane(float v, int k) {
    return __uint_as_float(__builtin_amdgcn_readlane(__float_as_uint(v), k));
}

// 4 waves per batch element (one gate type each). Cross-wave gate exchange
// uses an LDS flag protocol instead of s_barrier:
//   producer: write gates -> s_waitcnt lgkmcnt(0) -> publish flags[w]=t+1
//   consumer: poll flags[0..3] >= t+1 -> read gates
// DS ops are serviced in order per wave, so a data read issued after the
// successful flag read observes the published gates. Double-buffered gbuf
// + monotonic flags make buffer reuse safe (the data poll of step t-1
// already implies all waves finished reading buffer t%2 from step t-2).
__global__ __launch_bounds__(256, 1) void lstm_flag_kernel(
    const float* __restrict__ y,    // [B, T, D]
    const float* __restrict__ Wx,   // [D, 4H]
    const float* __restrict__ Wh,   // [H, 4H]
    const float* __restrict__ b,    // [4H]
    float* __restrict__ out)        // [B, T, H]
{
    const int j = threadIdx.x;        // gate column 0..255
    const int w = j >> 6;             // wave id = gate type (0=i,1=f,2=g,3=o)
    const int l = j & 63;             // lane = hidden unit
    const int batch = blockIdx.x;

    __shared__ float gbuf[2][HH][4];      // [buf][unit][gate]: b128 read per lane
    __shared__ volatile int flags[4];     // steps completed-writing, per wave

    // weight columns in registers (coalesced: fixed k, consecutive j)
    float wx[DD];
#pragma unroll
    for (int k = 0; k < DD; ++k) wx[k] = Wx[k * GG + j];
    float wh[HH];
#pragma unroll
    for (int k = 0; k < HH; ++k) wh[k] = Wh[k * GG + j];
    const float bj = b[j];

    // wave-uniform activation: sigmoid for i,f,o; tanh(x)=2*sig(2x)-1 for g
    const bool isg = (w == 2);
    const float sc = isg ? 2.0f : 1.0f;
    const float aa = isg ? 2.0f : 1.0f;
    const float ab = isg ? -1.0f : 0.0f;

    float c = 0.0f, h = 0.0f;         // lane l's replica of c[l], h[l]
    if (l == 0) flags[w] = 0;

    const float* ybase = y + (size_t)batch * (TT * DD);
    float* obase = out + (size_t)batch * (TT * HH);

    // x row double-buffered in registers, prefetched one step ahead
    float4 xa[DD / 4], xb[DD / 4];
    {
        const float4* r0 = (const float4*)ybase;
#pragma unroll
        for (int q = 0; q < DD / 4; ++q) xa[q] = r0[q];
    }

    __syncthreads();   // once: flags init visible before any publish/poll

#define STEP(XC, XN, BUFI, TI)                                                 \
    {                                                                          \
        /* prefetch next x row; stays in flight (no vmcnt waits anywhere) */   \
        const int tn_ = ((TI) + 1 < TT) ? ((TI) + 1) : (TI);                   \
        const float4* nrow_ = (const float4*)(ybase + (size_t)tn_ * DD);       \
        _Pragma("unroll")                                                      \
        for (int q = 0; q < DD / 4; ++q) XN[q] = nrow_[q];                     \
        /* gates: 4-way ILP accumulators, x part from regs */                  \
        float ac0 = bj, ac1 = 0.0f, ac2 = 0.0f, ac3 = 0.0f;                    \
        _Pragma("unroll")                                                      \
        for (int q = 0; q < DD / 4; ++q) {                                     \
            ac0 = fmaf(XC[q].x, wx[4 * q + 0], ac0);                           \
            ac1 = fmaf(XC[q].y, wx[4 * q + 1], ac1);                           \
            ac2 = fmaf(XC[q].z, wx[4 * q + 2], ac2);                           \
            ac3 = fmaf(XC[q].w, wx[4 * q + 3], ac3);                           \
        }                                                                      \
        /* h part: readlane broadcast, zero LDS */                             \
        _Pragma("unroll")                                                      \
        for (int k4 = 0; k4 < HH / 4; ++k4) {                                  \
            ac0 = fmaf(rdlane(h, 4 * k4 + 0), wh[4 * k4 + 0], ac0);            \
            ac1 = fmaf(rdlane(h, 4 * k4 + 1), wh[4 * k4 + 1], ac1);            \
            ac2 = fmaf(rdlane(h, 4 * k4 + 2), wh[4 * k4 + 2], ac2);            \
            ac3 = fmaf(rdlane(h, 4 * k4 + 3), wh[4 * k4 + 3], ac3);            \
        }                                                                      \
        float g_ = (ac0 + ac1) + (ac2 + ac3);                                  \
        gbuf[BUFI][l][w] = fmaf(aa, fast_sig(sc * g_), ab);                    \
        /* drain the gate write, then publish */                               \
        asm volatile("s_waitcnt lgkmcnt(0)" ::: "memory");                     \
        if (l == 0) flags[w] = (TI) + 1;                                       \
        /* single poll: wait for all four gate segments of this step */        \
        int f0_, f1_, f2_, f3_;                                                \
        do {                                                                   \
            f0_ = flags[0]; f1_ = flags[1]; f2_ = flags[2]; f3_ = flags[3];    \
        } while (f0_ < (TI) + 1 || f1_ < (TI) + 1 ||                           \
                 f2_ < (TI) + 1 || f3_ < (TI) + 1);                            \
        asm volatile("" ::: "memory");  /* no hoisting of the data read */     \
        float4 gv = *(const float4*)&gbuf[BUFI][l][0];                         \
        /* every wave redundantly updates its replica of (c, h) */             \
        c = fmaf(gv.y, c, gv.x * gv.z);                                        \
        h = gv.w * fmaf(2.0f, fast_sig(2.0f * c), -1.0f);   /* o*tanh(c) */    \
        if (w == 0) obase[(size_t)(TI) * HH + l] = h;                          \
    }

    for (int t = 0; t < TT; t += 2) {
        STEP(xa, xb, 0, t);       // consume xa, prefetch xb
        STEP(xb, xa, 1, t + 1);   // consume xb, prefetch xa
    }
#undef STEP
}

extern "C" void kernel_launch(void* const* d_in, const int* in_sizes, int n_in,
                              void* d_out, int out_size, void* d_ws, size_t ws_size,
                              hipStream_t stream) {
    const float* y  = (const float*)d_in[0];
    const float* Wx = (const float*)d_in[1];
    const float* Wh = (const float*)d_in[2];
    const float* b  = (const float*)d_in[3];
    float* out = (float*)d_out;

    lstm_flag_kernel<<<BB, GG, 0, stream>>>(y, Wx, Wh, b, out);
}